// Round 10
// baseline (140.007 us; speedup 1.0000x reference)
//
#include <hip/hip_runtime.h>
#include <hip/hip_bf16.h>
#include <cstdint>
#include <cstddef>

// Problem dims (fixed by the reference)
#define NEXP   8
#define BATCH  8
#define NTOK   2048
#define DDIM   512
#define DFFDIM 2048
#define DCOND  512

typedef float  f32x4  __attribute__((ext_vector_type(4)));
typedef __bf16 bf16x8 __attribute__((ext_vector_type(8)));

using as1_cvoid = __attribute__((address_space(1))) const void;
using as3_void  = __attribute__((address_space(3))) void;

__device__ __forceinline__ void async_copy16(const void* g, void* l) {
  __builtin_amdgcn_global_load_lds((as1_cvoid*)g, (as3_void*)l, 16, 0, 0);
}

__device__ __forceinline__ unsigned short f2bf_bits(float f) {
  __hip_bfloat16 h = __float2bfloat16(f);
  return *reinterpret_cast<unsigned short*>(&h);
}

// fast tanh-approx gelu: 0.5v(1+tanh(z)) == v * sigmoid(2z)
__device__ __forceinline__ float gelu_fast(float v) {
  float y = v * fmaf(0.0713548162726f, v * v, 1.5957691216057f);
  float e = exp2f(-1.44269504089f * y);
  return v * __builtin_amdgcn_rcpf(1.0f + e);
}

// ---------------------------------------------------------------------------
// 1) scale/shift = cond[b] @ W_cond[route[b]] + b_cond[route[b]] -> ss[B][1024]
// ---------------------------------------------------------------------------
__global__ void mod_kernel(const float* __restrict__ cond,
                           const int* __restrict__ route,
                           const float* __restrict__ W_cond,
                           const float* __restrict__ b_cond,
                           float* __restrict__ ss) {
  const int b = blockIdx.y;
  const int m = route[b];
  const int tj = threadIdx.x & 63;
  const int cq = threadIdx.x >> 6;            // 0..3
  const int j = blockIdx.x * 64 + tj;
  const float* wc = W_cond + (size_t)m * DCOND * (2 * DDIM);
  const float* cb = cond + (size_t)b * DCOND;
  float acc = 0.f;
#pragma unroll 4
  for (int c = cq * 128; c < cq * 128 + 128; ++c)
    acc += cb[c] * wc[(size_t)c * (2 * DDIM) + j];
  __shared__ float red[4][64];
  red[cq][tj] = acc;
  __syncthreads();
  if (cq == 0) {
    float v = red[0][tj] + red[1][tj] + red[2][tj] + red[3][tj];
    ss[(size_t)b * (2 * DDIM) + j] = v + b_cond[(size_t)m * (2 * DDIM) + j];
  }
}

// ---------------------------------------------------------------------------
// 2) x_mod = bf16( x * (1+scale) + shift )   [B][N][D] bf16
// ---------------------------------------------------------------------------
__global__ void film_kernel(const float* __restrict__ x,
                            const float* __restrict__ ss,
                            __hip_bfloat16* __restrict__ xmod) {
  const size_t idx = (size_t)blockIdx.x * blockDim.x + threadIdx.x;
  const int d4 = (int)(idx & (DDIM / 4 - 1));
  const int b  = (int)(idx >> 18);
  const float4 xv = reinterpret_cast<const float4*>(x)[idx];
  const float4 sc = reinterpret_cast<const float4*>(ss + (size_t)b * 1024)[d4];
  const float4 sh = reinterpret_cast<const float4*>(ss + (size_t)b * 1024 + DDIM)[d4];
  float r0 = xv.x * (1.f + sc.x) + sh.x;
  float r1 = xv.y * (1.f + sc.y) + sh.y;
  float r2 = xv.z * (1.f + sc.z) + sh.z;
  float r3 = xv.w * (1.f + sc.w) + sh.w;
  ushort4 ov;
  ov.x = f2bf_bits(r0); ov.y = f2bf_bits(r1);
  ov.z = f2bf_bits(r2); ov.w = f2bf_bits(r3);
  reinterpret_cast<ushort4*>(xmod)[idx] = ov;
}

// ---------------------------------------------------------------------------
// 3) transpose + f32->bf16:  in [M][L][R] f32  ->  out [M][R][L] bf16
// ---------------------------------------------------------------------------
__global__ void transpose_cvt(const float* __restrict__ in,
                              __hip_bfloat16* __restrict__ outp,
                              int L, int R,
                              const int* __restrict__ route) {
  const int mi = blockIdx.z;
  bool used = false;
#pragma unroll
  for (int b = 0; b < BATCH; ++b) used |= (route[b] == mi);
  if (!used) return;

  __shared__ float tile[32][33];
  const float* inm = in + (size_t)mi * L * R;
  __hip_bfloat16* outm = outp + (size_t)mi * L * R;
  const int r0 = blockIdx.x * 32, l0 = blockIdx.y * 32;
  const int tx = threadIdx.x, ty = threadIdx.y;
#pragma unroll
  for (int i = 0; i < 32; i += 8)
    tile[ty + i][tx] = inm[(size_t)(l0 + ty + i) * R + r0 + tx];
  __syncthreads();
#pragma unroll
  for (int i = 0; i < 32; i += 8)
    outm[(size_t)(r0 + ty + i) * L + l0 + tx] = __float2bfloat16(tile[tx][ty + i]);
}

// ---------------------------------------------------------------------------
// 4) SINGLE-BUFFER GEMM (m97-exact structure): BM=BN=128, BK=64, 256 threads
//    (4 waves 2x2, wave-tile 64x64).  LDS 32 KB total -> 5 blocks/CU
//    (160/32), 20 waves/CU: TLP experiment — cross-block wave overlap covers
//    the per-block drain barrier (m114 mechanism; m97 ran 3/CU at 874 TF,
//    m99/m100 showed explicit dbuf adds nothing on top).  No prefetch, no
//    vmcnt asm: STAGE -> __syncthreads (vmcnt0 drain) -> reads+MFMA ->
//    __syncthreads -> loop.  Swizzle: R6-verified (LDS(r,c)=global(r,c^(r&7)),
//    linear gload_lds dest + inverse-swizzled source + swizzled ds_read;
//    measured conflicts = 0).
//    EPI=0: bf16(gelu(acc+bias));  EPI=1: f32(acc+bias).
// ---------------------------------------------------------------------------
template <int EPI>
__global__ __launch_bounds__(256) void gemm_sb(
    const __hip_bfloat16* __restrict__ Abase,
    const __hip_bfloat16* __restrict__ Btbase,
    const float* __restrict__ biasbase,
    void* __restrict__ outbase,
    const int* __restrict__ route,
    int Mdim, int Ndim, int Kdim, int tilesX) {
  const int bid  = blockIdx.x;
  const int b    = bid & 7;            // batch -> XCD
  const int tile = bid >> 3;
  const int bx   = tile % tilesX;
  const int by   = tile / tilesX;
  const int m = route[b];
  const __hip_bfloat16* A  = Abase  + (size_t)b * Mdim * Kdim;
  const __hip_bfloat16* Bt = Btbase + (size_t)m * Ndim * Kdim;
  const float* bias = biasbase + (size_t)m * Ndim;
  const int r0 = bx * 128;
  const int n0 = by * 128;

  __shared__ alignas(16) __hip_bfloat16 As[128 * 64];   // 16 KB
  __shared__ alignas(16) __hip_bfloat16 Bs[128 * 64];   // 16 KB

  const int t = threadIdx.x;
  const int w = t >> 6, l = t & 63;
  const int wr = w >> 1, wc = w & 1;   // 2x2 waves, wave-tile 64x64

  // staging: chunk c_lin = i*256 + t -> LDS row i*32 + (t>>3), chunk t&7.
  // LDS(row r, chunk c) holds global(row r, chunk c ^ (r&7)); dest linear.
  const int srow = t >> 3;                     // 0..31 within 32-row group
  const int scol = (t & 7) ^ ((t >> 3) & 7);   // inverse-swizzled 16B chunk

  const int lrow = l & 15, lq = l >> 4, lx = l & 7;
  f32x4 acc[4][4] = {};
  const int nt = Kdim >> 6;

  for (int kt = 0; kt < nt; ++kt) {
    const int k0 = kt * 64;
#pragma unroll
    for (int i = 0; i < 4; ++i)
      async_copy16(A + (size_t)(r0 + i * 32 + srow) * Kdim + k0 + scol * 8,
                   &As[(i * 256 + t) * 8]);
#pragma unroll
    for (int i = 0; i < 4; ++i)
      async_copy16(Bt + (size_t)(n0 + i * 32 + srow) * Kdim + k0 + scol * 8,
                   &Bs[(i * 256 + t) * 8]);
    __syncthreads();                    // drains vmcnt(0): tile landed

    bf16x8 af[4][2], bfr[4][2];
#pragma unroll
    for (int mb = 0; mb < 4; ++mb) {
      const int row = wr * 64 + mb * 16 + lrow;
      af[mb][0] = *reinterpret_cast<const bf16x8*>(&As[(row * 8 + ((0 + lq) ^ lx)) * 8]);
      af[mb][1] = *reinterpret_cast<const bf16x8*>(&As[(row * 8 + ((4 + lq) ^ lx)) * 8]);
    }
#pragma unroll
    for (int nb = 0; nb < 4; ++nb) {
      const int row = wc * 64 + nb * 16 + lrow;
      bfr[nb][0] = *reinterpret_cast<const bf16x8*>(&Bs[(row * 8 + ((0 + lq) ^ lx)) * 8]);
      bfr[nb][1] = *reinterpret_cast<const bf16x8*>(&Bs[(row * 8 + ((4 + lq) ^ lx)) * 8]);
    }
#pragma unroll
    for (int mb = 0; mb < 4; ++mb)
#pragma unroll
      for (int nb = 0; nb < 4; ++nb) {
        acc[mb][nb] = __builtin_amdgcn_mfma_f32_16x16x32_bf16(
            af[mb][0], bfr[nb][0], acc[mb][nb], 0, 0, 0);
        acc[mb][nb] = __builtin_amdgcn_mfma_f32_16x16x32_bf16(
            af[mb][1], bfr[nb][1], acc[mb][nb], 0, 0, 0);
      }

    __syncthreads();                    // reads done -> next stage may overwrite
  }

  // ---- epilogue: C/D layout col=lane&15, row=(lane>>4)*4+j ----
  if (EPI == 0) {
    __hip_bfloat16* out = (__hip_bfloat16*)outbase + (size_t)b * Mdim * Ndim;
#pragma unroll
    for (int mb = 0; mb < 4; ++mb) {
      const int row = r0 + wr * 64 + mb * 16 + lq * 4;
#pragma unroll
      for (int nb = 0; nb < 4; ++nb) {
        const int col = n0 + wc * 64 + nb * 16 + lrow;
        const float bv = bias[col];
#pragma unroll
        for (int j = 0; j < 4; ++j) {
          float g = gelu_fast(acc[mb][nb][j] + bv);
          out[(size_t)(row + j) * Ndim + col] = __float2bfloat16(g);
        }
      }
    }
  } else {
    float* out = (float*)outbase + (size_t)b * Mdim * Ndim;
#pragma unroll
    for (int mb = 0; mb < 4; ++mb) {
      const int row = r0 + wr * 64 + mb * 16 + lq * 4;
#pragma unroll
      for (int nb = 0; nb < 4; ++nb) {
        const int col = n0 + wc * 64 + nb * 16 + lrow;
        const float bv = bias[col];
#pragma unroll
        for (int j = 0; j < 4; ++j)
          out[(size_t)(row + j) * Ndim + col] = acc[mb][nb][j] + bv;
      }
    }
  }
}

// ---------------------------------------------------------------------------
extern "C" void kernel_launch(void* const* d_in, const int* in_sizes, int n_in,
                              void* d_out, int out_size, void* d_ws, size_t ws_size,
                              hipStream_t stream) {
  const float* x      = (const float*)d_in[0];
  const float* cond   = (const float*)d_in[1];
  const int*   route  = (const int*)d_in[2];
  const float* W_cond = (const float*)d_in[3];
  const float* b_cond = (const float*)d_in[4];
  const float* W1     = (const float*)d_in[5];
  const float* b1     = (const float*)d_in[6];
  const float* W2     = (const float*)d_in[7];
  const float* b2     = (const float*)d_in[8];
  float* out = (float*)d_out;

  // workspace layout (bytes)
  const size_t SS_OFF   = 0;
  const size_t XMOD_OFF = 32768;
  const size_t W1T_OFF  = XMOD_OFF + (size_t)BATCH * NTOK * DDIM * 2;
  const size_t W2T_OFF  = W1T_OFF + (size_t)NEXP * DDIM * DFFDIM * 2;
  const size_t H_OFF    = W2T_OFF + (size_t)NEXP * DFFDIM * DDIM * 2;
  const size_t NEED     = H_OFF + (size_t)BATCH * NTOK * DFFDIM * 2;
  if (ws_size < NEED) return;

  char* ws = (char*)d_ws;
  float* ss            = (float*)(ws + SS_OFF);
  __hip_bfloat16* xmod = (__hip_bfloat16*)(ws + XMOD_OFF);
  __hip_bfloat16* w1t  = (__hip_bfloat16*)(ws + W1T_OFF);
  __hip_bfloat16* w2t  = (__hip_bfloat16*)(ws + W2T_OFF);
  __hip_bfloat16* h    = (__hip_bfloat16*)(ws + H_OFF);

  // 1) cond modulation
  mod_kernel<<<dim3(2 * DDIM / 64, BATCH), 256, 0, stream>>>(cond, route, W_cond, b_cond, ss);

  // 2) FiLM -> bf16
  {
    const size_t groups = (size_t)BATCH * NTOK * DDIM / 4;
    film_kernel<<<(unsigned)(groups / 256), 256, 0, stream>>>(x, ss, xmod);
  }

  // 3) weight transpose+convert (routed experts only)
  transpose_cvt<<<dim3(DFFDIM / 32, DDIM / 32, NEXP), dim3(32, 8), 0, stream>>>(W1, w1t, DDIM, DFFDIM, route);
  transpose_cvt<<<dim3(DDIM / 32, DFFDIM / 32, NEXP), dim3(32, 8), 0, stream>>>(W2, w2t, DFFDIM, DDIM, route);

  // 4) GEMM1: h = gelu(xmod @ W1 + b1)   grid 16*16*8 = 2048 blocks
  gemm_sb<0><<<(NTOK / 128) * (DFFDIM / 128) * BATCH, 256, 0, stream>>>(
      xmod, w1t, b1, h, route, NTOK, DFFDIM, DDIM, NTOK / 128);

  // 5) GEMM2: out = h @ W2 + b2          grid 16*4*8 = 512 blocks
  gemm_sb<1><<<(NTOK / 128) * (DDIM / 128) * BATCH, 256, 0, stream>>>(
      h, w2t, b2, out, route, NTOK, DDIM, DFFDIM, NTOK / 128);
}

// Round 11
// 137.472 us; speedup vs baseline: 1.0184x; 1.0184x over previous
//
#include <hip/hip_runtime.h>
#include <hip/hip_bf16.h>
#include <cstdint>
#include <cstddef>

// Problem dims (fixed by the reference)
#define NEXP   8
#define BATCH  8
#define NTOK   2048
#define DDIM   512
#define DFFDIM 2048
#define DCOND  512

typedef float  f32x4  __attribute__((ext_vector_type(4)));
typedef __bf16 bf16x8 __attribute__((ext_vector_type(8)));

using as1_cvoid = __attribute__((address_space(1))) const void;
using as3_void  = __attribute__((address_space(3))) void;

__device__ __forceinline__ void async_copy16(const void* g, void* l) {
  __builtin_amdgcn_global_load_lds((as1_cvoid*)g, (as3_void*)l, 16, 0, 0);
}

__device__ __forceinline__ unsigned short f2bf_bits(float f) {
  __hip_bfloat16 h = __float2bfloat16(f);
  return *reinterpret_cast<unsigned short*>(&h);
}

// fast tanh-approx gelu: 0.5v(1+tanh(z)) == v * sigmoid(2z)
__device__ __forceinline__ float gelu_fast(float v) {
  float y = v * fmaf(0.0713548162726f, v * v, 1.5957691216057f);
  float e = exp2f(-1.44269504089f * y);
  return v * __builtin_amdgcn_rcpf(1.0f + e);
}

// ---------------------------------------------------------------------------
// 1) scale/shift = cond[b] @ W_cond[route[b]] + b_cond[route[b]] -> ss[B][1024]
// ---------------------------------------------------------------------------
__global__ void mod_kernel(const float* __restrict__ cond,
                           const int* __restrict__ route,
                           const float* __restrict__ W_cond,
                           const float* __restrict__ b_cond,
                           float* __restrict__ ss) {
  const int b = blockIdx.y;
  const int m = route[b];
  const int tj = threadIdx.x & 63;
  const int cq = threadIdx.x >> 6;            // 0..3
  const int j = blockIdx.x * 64 + tj;
  const float* wc = W_cond + (size_t)m * DCOND * (2 * DDIM);
  const float* cb = cond + (size_t)b * DCOND;
  float acc = 0.f;
#pragma unroll 4
  for (int c = cq * 128; c < cq * 128 + 128; ++c)
    acc += cb[c] * wc[(size_t)c * (2 * DDIM) + j];
  __shared__ float red[4][64];
  red[cq][tj] = acc;
  __syncthreads();
  if (cq == 0) {
    float v = red[0][tj] + red[1][tj] + red[2][tj] + red[3][tj];
    ss[(size_t)b * (2 * DDIM) + j] = v + b_cond[(size_t)m * (2 * DDIM) + j];
  }
}

// ---------------------------------------------------------------------------
// 2) x_mod = bf16( x * (1+scale) + shift )   [B][N][D] bf16
// ---------------------------------------------------------------------------
__global__ void film_kernel(const float* __restrict__ x,
                            const float* __restrict__ ss,
                            __hip_bfloat16* __restrict__ xmod) {
  const size_t idx = (size_t)blockIdx.x * blockDim.x + threadIdx.x;
  const int d4 = (int)(idx & (DDIM / 4 - 1));
  const int b  = (int)(idx >> 18);
  const float4 xv = reinterpret_cast<const float4*>(x)[idx];
  const float4 sc = reinterpret_cast<const float4*>(ss + (size_t)b * 1024)[d4];
  const float4 sh = reinterpret_cast<const float4*>(ss + (size_t)b * 1024 + DDIM)[d4];
  float r0 = xv.x * (1.f + sc.x) + sh.x;
  float r1 = xv.y * (1.f + sc.y) + sh.y;
  float r2 = xv.z * (1.f + sc.z) + sh.z;
  float r3 = xv.w * (1.f + sc.w) + sh.w;
  ushort4 ov;
  ov.x = f2bf_bits(r0); ov.y = f2bf_bits(r1);
  ov.z = f2bf_bits(r2); ov.w = f2bf_bits(r3);
  reinterpret_cast<ushort4*>(xmod)[idx] = ov;
}

// ---------------------------------------------------------------------------
// 3) transpose + f32->bf16:  in [M][L][R] f32  ->  out [M][R][L] bf16
// ---------------------------------------------------------------------------
__global__ void transpose_cvt(const float* __restrict__ in,
                              __hip_bfloat16* __restrict__ outp,
                              int L, int R,
                              const int* __restrict__ route) {
  const int mi = blockIdx.z;
  bool used = false;
#pragma unroll
  for (int b = 0; b < BATCH; ++b) used |= (route[b] == mi);
  if (!used) return;

  __shared__ float tile[32][33];
  const float* inm = in + (size_t)mi * L * R;
  __hip_bfloat16* outm = outp + (size_t)mi * L * R;
  const int r0 = blockIdx.x * 32, l0 = blockIdx.y * 32;
  const int tx = threadIdx.x, ty = threadIdx.y;
#pragma unroll
  for (int i = 0; i < 32; i += 8)
    tile[ty + i][tx] = inm[(size_t)(l0 + ty + i) * R + r0 + tx];
  __syncthreads();
#pragma unroll
  for (int i = 0; i < 32; i += 8)
    outm[(size_t)(r0 + ty + i) * L + l0 + tx] = __float2bfloat16(tile[tx][ty + i]);
}

// ---------------------------------------------------------------------------
// 4a) 8-PHASE GEMM1 (R9-proven, unchanged): BM=BN=256, BK=64, 512 threads.
// ---------------------------------------------------------------------------
template <int EPI>
__global__ __launch_bounds__(512, 1) void gemm_8ph(
    const __hip_bfloat16* __restrict__ A,
    const __hip_bfloat16* __restrict__ Btb,
    const float* __restrict__ biasbase,
    void* __restrict__ outbase,
    const int* __restrict__ route,
    int Mdim, int Ndim, int Kdim, int tilesX) {
  const int bid  = blockIdx.x;
  const int b    = bid & 7;            // batch -> XCD
  const int tile = bid >> 3;
  const int bx   = tile % tilesX;
  const int by   = tile / tilesX;
  const int m = route[b];
  const __hip_bfloat16* Ab = A   + (size_t)b * Mdim * Kdim;
  const __hip_bfloat16* Bt = Btb + (size_t)m * Ndim * Kdim;
  const float* bias = biasbase + (size_t)m * Ndim;
  const int r0 = bx * 256;
  const int n0 = by * 256;

  __shared__ alignas(16) __hip_bfloat16 As[2][2][128 * 64];  // 64 KB
  __shared__ alignas(16) __hip_bfloat16 Bs[2][2][128 * 64];  // 64 KB

  const int t = threadIdx.x;
  const int w = t >> 6, l = t & 63;
  const int wm = w >> 2;               // 0..1  (M half, 128 rows)
  const int wn = w & 3;                // 0..3  (N quarter, 64 cols)

  const int srow = t >> 3;                     // 0..63
  const int scol = (t & 7) ^ ((t >> 3) & 7);   // inverse-swizzled 16B chunk

#define STAGE_AH(sb, ha, k0)                                                  \
  { async_copy16(Ab + (size_t)(r0 + (ha) * 128 + srow) * Kdim + (k0) + scol * 8, \
                 &As[sb][ha][(size_t)t * 8]);                                 \
    async_copy16(Ab + (size_t)(r0 + (ha) * 128 + 64 + srow) * Kdim + (k0) + scol * 8, \
                 &As[sb][ha][(size_t)(512 + t) * 8]); }
#define STAGE_BH(sb, hb, k0)                                                  \
  { async_copy16(Bt + (size_t)(n0 + (hb) * 128 + srow) * Kdim + (k0) + scol * 8, \
                 &Bs[sb][hb][(size_t)t * 8]);                                 \
    async_copy16(Bt + (size_t)(n0 + (hb) * 128 + 64 + srow) * Kdim + (k0) + scol * 8, \
                 &Bs[sb][hb][(size_t)(512 + t) * 8]); }

  const int lrow = l & 15, lq = l >> 4, lx = l & 7;

#define LOAD_A(mh)                                                            \
  { _Pragma("unroll")                                                         \
    for (int i = 0; i < 4; ++i) {                                             \
      const int row = ((mh) * 4 + i) * 16 + lrow;                             \
      aF[i][0] = *reinterpret_cast<const bf16x8*>(&aH[(row * 8 + ((0 + lq) ^ lx)) * 8]); \
      aF[i][1] = *reinterpret_cast<const bf16x8*>(&aH[(row * 8 + ((4 + lq) ^ lx)) * 8]); \
    } }
#define LOAD_B(nh)                                                            \
  { _Pragma("unroll")                                                         \
    for (int j = 0; j < 2; ++j) {                                             \
      const int row = (wn & 1) * 64 + ((nh) * 2 + j) * 16 + lrow;             \
      bF[nh][j][0] = *reinterpret_cast<const bf16x8*>(&bH[(row * 8 + ((0 + lq) ^ lx)) * 8]); \
      bF[nh][j][1] = *reinterpret_cast<const bf16x8*>(&bH[(row * 8 + ((4 + lq) ^ lx)) * 8]); \
    } }
#define MFMA_Q(mh, nh)                                                        \
  { __builtin_amdgcn_s_setprio(1);                                            \
    _Pragma("unroll")                                                         \
    for (int i = 0; i < 4; ++i)                                               \
      _Pragma("unroll")                                                       \
      for (int j = 0; j < 2; ++j) {                                           \
        acc[(mh) * 4 + i][(nh) * 2 + j] = __builtin_amdgcn_mfma_f32_16x16x32_bf16( \
            aF[i][0], bF[nh][j][0], acc[(mh) * 4 + i][(nh) * 2 + j], 0, 0, 0);\
        acc[(mh) * 4 + i][(nh) * 2 + j] = __builtin_amdgcn_mfma_f32_16x16x32_bf16( \
            aF[i][1], bF[nh][j][1], acc[(mh) * 4 + i][(nh) * 2 + j], 0, 0, 0);\
      }                                                                       \
    __builtin_amdgcn_s_setprio(0); }
#define BARSCHED  { __builtin_amdgcn_s_barrier(); __builtin_amdgcn_sched_barrier(0); }

  f32x4 acc[8][4] = {};
  const int nt = Kdim >> 6;

  STAGE_BH(0, 0, 0)
  STAGE_AH(0, 0, 0)
  STAGE_AH(0, 1, 0)
  STAGE_BH(0, 1, 0)
  if (nt > 1) { STAGE_BH(1, 0, 64) STAGE_AH(1, 0, 64) }

  for (int kt = 0; kt < nt; ++kt) {
    const int s = kt & 1;
    if (kt == nt - 1) { asm volatile("s_waitcnt vmcnt(0)" ::: "memory"); }
    else              { asm volatile("s_waitcnt vmcnt(4)" ::: "memory"); }
    BARSCHED

    const __hip_bfloat16* aH = As[s][wm];
    const __hip_bfloat16* bH = Bs[s][wn >> 1];
    bf16x8 aF[4][2], bF[2][2][2];

    LOAD_A(0)
    LOAD_B(0)
    if (kt + 1 < nt) STAGE_AH(s ^ 1, 1, (kt + 1) * 64)
    BARSCHED
    MFMA_Q(0, 0)
    BARSCHED

    LOAD_B(1)
    if (kt + 1 < nt) STAGE_BH(s ^ 1, 1, (kt + 1) * 64)
    BARSCHED
    MFMA_Q(0, 1)
    BARSCHED

    LOAD_A(1)
    if (kt + 2 < nt) STAGE_BH(s, 0, (kt + 2) * 64)
    BARSCHED
    MFMA_Q(1, 0)
    BARSCHED

    if (kt + 2 < nt) STAGE_AH(s, 0, (kt + 2) * 64)
    MFMA_Q(1, 1)
  }
#undef STAGE_AH
#undef STAGE_BH
#undef LOAD_A
#undef LOAD_B
#undef MFMA_Q
#undef BARSCHED

  if (EPI == 0) {
    __hip_bfloat16* out = (__hip_bfloat16*)outbase + (size_t)b * Mdim * Ndim;
#pragma unroll
    for (int mb = 0; mb < 8; ++mb) {
      const int row = r0 + wm * 128 + mb * 16 + lq * 4;
#pragma unroll
      for (int nb = 0; nb < 4; ++nb) {
        const int col = n0 + wn * 64 + nb * 16 + lrow;
        const float bv = bias[col];
#pragma unroll
        for (int j = 0; j < 4; ++j) {
          float g = gelu_fast(acc[mb][nb][j] + bv);
          out[(size_t)(row + j) * Ndim + col] = __float2bfloat16(g);
        }
      }
    }
  } else {
    float* out = (float*)outbase + (size_t)b * Mdim * Ndim;
#pragma unroll
    for (int mb = 0; mb < 8; ++mb) {
      const int row = r0 + wm * 128 + mb * 16 + lq * 4;
#pragma unroll
      for (int nb = 0; nb < 4; ++nb) {
        const int col = n0 + wn * 64 + nb * 16 + lrow;
        const float bv = bias[col];
#pragma unroll
        for (int j = 0; j < 4; ++j)
          out[(size_t)(row + j) * Ndim + col] = acc[mb][nb][j] + bv;
      }
    }
  }
}

// ---------------------------------------------------------------------------
// 4b) 8-PHASE GEMM2: BM=256, BN=128, BK=64, 512 threads = 8 waves (2M x 4N),
//     wave-tile 128x32 (acc 8x2).  Grid 8*4*8 = 256 blocks = exactly 1/CU,
//     single round, nt=32 amortizes pipeline fill.  LDS 96 KB:
//     As[2][2][128x64] (A halves 128 rows, 2 loads/thread),
//     Bs[2][2][64x64]  (B halves 64 rows, 1 load/thread).
//     Ledger: per K-tile stages A1(k+1)[2] ph0, B1(k+1)[1] ph1,
//     B0(k+2)[1] ph2, A0(k+2)[2] ph3.  Entry wait vmcnt(3): newest 3 ops =
//     B0(kt+1)+A0(kt+1); retires all 4 halves of tile kt.  Safety: all B
//     reads end at ph1-barrier (each wave reads only its own half, nh=0/1 in
//     ph0/ph1) -> B0(kt+2) staged ph2 OK; all A reads end at ph2-barrier
//     (LOAD_A(0) ph0, LOAD_A(1) ph2) -> A0(kt+2) staged ph3 OK; ph0/ph1
//     stage into the opposite buffer.  Swizzle identical to GEMM1.
// ---------------------------------------------------------------------------
__global__ __launch_bounds__(512, 1) void gemm2_8ph(
    const __hip_bfloat16* __restrict__ A,
    const __hip_bfloat16* __restrict__ Btb,
    const float* __restrict__ biasbase,
    float* __restrict__ outb,
    const int* __restrict__ route,
    int Mdim, int Ndim, int Kdim, int tilesX) {
  const int bid  = blockIdx.x;
  const int b    = bid & 7;            // batch -> XCD
  const int tile = bid >> 3;
  const int bx   = tile % tilesX;      // M-tile (256 rows)
  const int by   = tile / tilesX;      // N-tile (128 cols)
  const int m = route[b];
  const __hip_bfloat16* Ab = A   + (size_t)b * Mdim * Kdim;
  const __hip_bfloat16* Bt = Btb + (size_t)m * Ndim * Kdim;
  const float* bias = biasbase + (size_t)m * Ndim;
  const int r0 = bx * 256;
  const int n0 = by * 128;

  __shared__ alignas(16) __hip_bfloat16 As[2][2][128 * 64];  // 64 KB
  __shared__ alignas(16) __hip_bfloat16 Bs[2][2][64 * 64];   // 32 KB

  const int t = threadIdx.x;
  const int w = t >> 6, l = t & 63;
  const int wm = w >> 2;               // 0..1  M half (128 rows)
  const int wn = w & 3;                // 0..3  N quarter (32 cols)

  const int srow = t >> 3;                     // 0..63
  const int scol = (t & 7) ^ ((t >> 3) & 7);

#define STAGE_AH2(sb, ha, k0)                                                 \
  { async_copy16(Ab + (size_t)(r0 + (ha) * 128 + srow) * Kdim + (k0) + scol * 8, \
                 &As[sb][ha][(size_t)t * 8]);                                 \
    async_copy16(Ab + (size_t)(r0 + (ha) * 128 + 64 + srow) * Kdim + (k0) + scol * 8, \
                 &As[sb][ha][(size_t)(512 + t) * 8]); }
#define STAGE_BH2(sb, hb, k0)                                                 \
  { async_copy16(Bt + (size_t)(n0 + (hb) * 64 + srow) * Kdim + (k0) + scol * 8, \
                 &Bs[sb][hb][(size_t)t * 8]); }

  const int lrow = l & 15, lq = l >> 4, lx = l & 7;

#define LOAD_A2(mh)                                                           \
  { _Pragma("unroll")                                                         \
    for (int i = 0; i < 4; ++i) {                                             \
      const int row = ((mh) * 4 + i) * 16 + lrow;                             \
      aF[i][0] = *reinterpret_cast<const bf16x8*>(&aH[(row * 8 + ((0 + lq) ^ lx)) * 8]); \
      aF[i][1] = *reinterpret_cast<const bf16x8*>(&aH[(row * 8 + ((4 + lq) ^ lx)) * 8]); \
    } }
#define LOAD_B2(nh)                                                           \
  { const int row = (wn & 1) * 32 + (nh) * 16 + lrow;                         \
    bF[nh][0] = *reinterpret_cast<const bf16x8*>(&bH[(row * 8 + ((0 + lq) ^ lx)) * 8]); \
    bF[nh][1] = *reinterpret_cast<const bf16x8*>(&bH[(row * 8 + ((4 + lq) ^ lx)) * 8]); }
#define MFMA_Q2(mh, nh)                                                       \
  { __builtin_amdgcn_s_setprio(1);                                            \
    _Pragma("unroll")                                                         \
    for (int i = 0; i < 4; ++i) {                                             \
      acc[(mh) * 4 + i][nh] = __builtin_amdgcn_mfma_f32_16x16x32_bf16(        \
          aF[i][0], bF[nh][0], acc[(mh) * 4 + i][nh], 0, 0, 0);               \
      acc[(mh) * 4 + i][nh] = __builtin_amdgcn_mfma_f32_16x16x32_bf16(        \
          aF[i][1], bF[nh][1], acc[(mh) * 4 + i][nh], 0, 0, 0);               \
    }                                                                         \
    __builtin_amdgcn_s_setprio(0); }
#define BARSCHED  { __builtin_amdgcn_s_barrier(); __builtin_amdgcn_sched_barrier(0); }

  f32x4 acc[8][2] = {};
  const int nt = Kdim >> 6;            // 32

  // prologue: tile 0 complete (6 ops), then B0(1),A0(1) as the NEWEST 3 ops
  STAGE_AH2(0, 0, 0)
  STAGE_AH2(0, 1, 0)
  STAGE_BH2(0, 0, 0)
  STAGE_BH2(0, 1, 0)
  if (nt > 1) { STAGE_BH2(1, 0, 64) STAGE_AH2(1, 0, 64) }

  for (int kt = 0; kt < nt; ++kt) {
    const int s = kt & 1;
    if (kt == nt - 1) { asm volatile("s_waitcnt vmcnt(0)" ::: "memory"); }
    else              { asm volatile("s_waitcnt vmcnt(3)" ::: "memory"); }
    BARSCHED

    const __hip_bfloat16* aH = As[s][wm];
    const __hip_bfloat16* bH = Bs[s][wn >> 1];
    bf16x8 aF[4][2], bF[2][2];

    // ph0: read A(0)+B(0); stage A1(kt+1) -> opposite buf; quadrant (0,0)
    LOAD_A2(0)
    LOAD_B2(0)
    if (kt + 1 < nt) STAGE_AH2(s ^ 1, 1, (kt + 1) * 64)
    BARSCHED
    MFMA_Q2(0, 0)
    BARSCHED

    // ph1: read B(1); stage B1(kt+1) -> opposite buf; quadrant (0,1)
    LOAD_B2(1)
    if (kt + 1 < nt) STAGE_BH2(s ^ 1, 1, (kt + 1) * 64)
    BARSCHED
    MFMA_Q2(0, 1)
    BARSCHED

    // ph2: read A(1); stage B0(kt+2) -> current buf (B reads done); (1,0)
    LOAD_A2(1)
    if (kt + 2 < nt) STAGE_BH2(s, 0, (kt + 2) * 64)
    BARSCHED
    MFMA_Q2(1, 0)
    BARSCHED

    // ph3: stage A0(kt+2) -> current buf (A reads done); quadrant (1,1)
    if (kt + 2 < nt) STAGE_AH2(s, 0, (kt + 2) * 64)
    MFMA_Q2(1, 1)
  }
#undef STAGE_AH2
#undef STAGE_BH2
#undef LOAD_A2
#undef LOAD_B2
#undef MFMA_Q2
#undef BARSCHED

  // epilogue: f32 out + bias.  C/D layout col=lane&15, row=(lane>>4)*4+j
  float* out = outb + (size_t)b * Mdim * Ndim;
#pragma unroll
  for (int mb = 0; mb < 8; ++mb) {
    const int row = r0 + wm * 128 + mb * 16 + lq * 4;
#pragma unroll
    for (int nb = 0; nb < 2; ++nb) {
      const int col = n0 + wn * 32 + nb * 16 + lrow;
      const float bv = bias[col];
#pragma unroll
      for (int j = 0; j < 4; ++j)
        out[(size_t)(row + j) * Ndim + col] = acc[mb][nb][j] + bv;
    }
  }
}

// ---------------------------------------------------------------------------
extern "C" void kernel_launch(void* const* d_in, const int* in_sizes, int n_in,
                              void* d_out, int out_size, void* d_ws, size_t ws_size,
                              hipStream_t stream) {
  const float* x      = (const float*)d_in[0];
  const float* cond   = (const float*)d_in[1];
  const int*   route  = (const int*)d_in[2];
  const float* W_cond = (const float*)d_in[3];
  const float* b_cond = (const float*)d_in[4];
  const float* W1     = (const float*)d_in[5];
  const float* b1     = (const float*)d_in[6];
  const float* W2     = (const float*)d_in[7];
  const float* b2     = (const float*)d_in[8];
  float* out = (float*)d_out;

  // workspace layout (bytes)
  const size_t SS_OFF   = 0;
  const size_t XMOD_OFF = 32768;
  const size_t W1T_OFF  = XMOD_OFF + (size_t)BATCH * NTOK * DDIM * 2;
  const size_t W2T_OFF  = W1T_OFF + (size_t)NEXP * DDIM * DFFDIM * 2;
  const size_t H_OFF    = W2T_OFF + (size_t)NEXP * DFFDIM * DDIM * 2;
  const size_t NEED     = H_OFF + (size_t)BATCH * NTOK * DFFDIM * 2;
  if (ws_size < NEED) return;

  char* ws = (char*)d_ws;
  float* ss            = (float*)(ws + SS_OFF);
  __hip_bfloat16* xmod = (__hip_bfloat16*)(ws + XMOD_OFF);
  __hip_bfloat16* w1t  = (__hip_bfloat16*)(ws + W1T_OFF);
  __hip_bfloat16* w2t  = (__hip_bfloat16*)(ws + W2T_OFF);
  __hip_bfloat16* h    = (__hip_bfloat16*)(ws + H_OFF);

  // 1) cond modulation
  mod_kernel<<<dim3(2 * DDIM / 64, BATCH), 256, 0, stream>>>(cond, route, W_cond, b_cond, ss);

  // 2) FiLM -> bf16
  {
    const size_t groups = (size_t)BATCH * NTOK * DDIM / 4;
    film_kernel<<<(unsigned)(groups / 256), 256, 0, stream>>>(x, ss, xmod);
  }

  // 3) weight transpose+convert (routed experts only)
  transpose_cvt<<<dim3(DFFDIM / 32, DDIM / 32, NEXP), dim3(32, 8), 0, stream>>>(W1, w1t, DDIM, DFFDIM, route);
  transpose_cvt<<<dim3(DDIM / 32, DFFDIM / 32, NEXP), dim3(32, 8), 0, stream>>>(W2, w2t, DFFDIM, DDIM, route);

  // 4) GEMM1 (8-phase 256x256, R9-proven): grid 8*8*8 = 512 blocks
  gemm_8ph<0><<<(NTOK / 256) * (DFFDIM / 256) * BATCH, 512, 0, stream>>>(
      xmod, w1t, b1, h, route, NTOK, DFFDIM, DDIM, NTOK / 256);

  // 5) GEMM2 (8-phase 256x128): grid 8*4*8 = 256 blocks = 1/CU exactly
  gemm2_8ph<<<(NTOK / 256) * (DDIM / 128) * BATCH, 512, 0, stream>>>(
      h, w2t, b2, out, route, NTOK, DDIM, DFFDIM, NTOK / 256);
}

// Round 12
// 129.597 us; speedup vs baseline: 1.0803x; 1.0608x over previous
//
#include <hip/hip_runtime.h>
#include <hip/hip_bf16.h>
#include <cstdint>
#include <cstddef>

// Problem dims (fixed by the reference)
#define NEXP   8
#define BATCH  8
#define NTOK   2048
#define DDIM   512
#define DFFDIM 2048
#define DCOND  512

typedef float  f32x4  __attribute__((ext_vector_type(4)));
typedef __bf16 bf16x8 __attribute__((ext_vector_type(8)));

using as1_cvoid = __attribute__((address_space(1))) const void;
using as3_void  = __attribute__((address_space(3))) void;

__device__ __forceinline__ void async_copy16(const void* g, void* l) {
  __builtin_amdgcn_global_load_lds((as1_cvoid*)g, (as3_void*)l, 16, 0, 0);
}

__device__ __forceinline__ unsigned short f2bf_bits(float f) {
  __hip_bfloat16 h = __float2bfloat16(f);
  return *reinterpret_cast<unsigned short*>(&h);
}

// fast tanh-approx gelu: 0.5v(1+tanh(z)) == v * sigmoid(2z)
__device__ __forceinline__ float gelu_fast(float v) {
  float y = v * fmaf(0.0713548162726f, v * v, 1.5957691216057f);
  float e = exp2f(-1.44269504089f * y);
  return v * __builtin_amdgcn_rcpf(1.0f + e);
}

// ---------------------------------------------------------------------------
// 1) scale/shift = cond[b] @ W_cond[route[b]] + b_cond[route[b]] -> ss[B][1024]
// ---------------------------------------------------------------------------
__global__ void mod_kernel(const float* __restrict__ cond,
                           const int* __restrict__ route,
                           const float* __restrict__ W_cond,
                           const float* __restrict__ b_cond,
                           float* __restrict__ ss) {
  const int b = blockIdx.y;
  const int m = route[b];
  const int tj = threadIdx.x & 63;
  const int cq = threadIdx.x >> 6;            // 0..3
  const int j = blockIdx.x * 64 + tj;
  const float* wc = W_cond + (size_t)m * DCOND * (2 * DDIM);
  const float* cb = cond + (size_t)b * DCOND;
  float acc = 0.f;
#pragma unroll 4
  for (int c = cq * 128; c < cq * 128 + 128; ++c)
    acc += cb[c] * wc[(size_t)c * (2 * DDIM) + j];
  __shared__ float red[4][64];
  red[cq][tj] = acc;
  __syncthreads();
  if (cq == 0) {
    float v = red[0][tj] + red[1][tj] + red[2][tj] + red[3][tj];
    ss[(size_t)b * (2 * DDIM) + j] = v + b_cond[(size_t)m * (2 * DDIM) + j];
  }
}

// ---------------------------------------------------------------------------
// 2) x_mod = bf16( x * (1+scale) + shift )   [B][N][D] bf16
// ---------------------------------------------------------------------------
__global__ void film_kernel(const float* __restrict__ x,
                            const float* __restrict__ ss,
                            __hip_bfloat16* __restrict__ xmod) {
  const size_t idx = (size_t)blockIdx.x * blockDim.x + threadIdx.x;
  const int d4 = (int)(idx & (DDIM / 4 - 1));
  const int b  = (int)(idx >> 18);
  const float4 xv = reinterpret_cast<const float4*>(x)[idx];
  const float4 sc = reinterpret_cast<const float4*>(ss + (size_t)b * 1024)[d4];
  const float4 sh = reinterpret_cast<const float4*>(ss + (size_t)b * 1024 + DDIM)[d4];
  float r0 = xv.x * (1.f + sc.x) + sh.x;
  float r1 = xv.y * (1.f + sc.y) + sh.y;
  float r2 = xv.z * (1.f + sc.z) + sh.z;
  float r3 = xv.w * (1.f + sc.w) + sh.w;
  ushort4 ov;
  ov.x = f2bf_bits(r0); ov.y = f2bf_bits(r1);
  ov.z = f2bf_bits(r2); ov.w = f2bf_bits(r3);
  reinterpret_cast<ushort4*>(xmod)[idx] = ov;
}

// ---------------------------------------------------------------------------
// 3) transpose + f32->bf16:  in [M][L][R] f32  ->  out [M][R][L] bf16
// ---------------------------------------------------------------------------
__global__ void transpose_cvt(const float* __restrict__ in,
                              __hip_bfloat16* __restrict__ outp,
                              int L, int R,
                              const int* __restrict__ route) {
  const int mi = blockIdx.z;
  bool used = false;
#pragma unroll
  for (int b = 0; b < BATCH; ++b) used |= (route[b] == mi);
  if (!used) return;

  __shared__ float tile[32][33];
  const float* inm = in + (size_t)mi * L * R;
  __hip_bfloat16* outm = outp + (size_t)mi * L * R;
  const int r0 = blockIdx.x * 32, l0 = blockIdx.y * 32;
  const int tx = threadIdx.x, ty = threadIdx.y;
#pragma unroll
  for (int i = 0; i < 32; i += 8)
    tile[ty + i][tx] = inm[(size_t)(l0 + ty + i) * R + r0 + tx];
  __syncthreads();
#pragma unroll
  for (int i = 0; i < 32; i += 8)
    outm[(size_t)(r0 + ty + i) * L + l0 + tx] = __float2bfloat16(tile[tx][ty + i]);
}

// ---------------------------------------------------------------------------
// 4a) 4-BARRIER 8-PHASE GEMM1: BM=BN=256, BK=64, 512 threads = 8 waves
//     (2M x 4N), wave-tile 128x64.  Same staging/ledger as R9's gemm_8ph,
//     but the mid-phase barrier between ds_reads and MFMA is REMOVED:
//     each phase = one scheduling region {ds_reads; stage; MFMA} ending in a
//     single barrier (4/tile).  MFMA's data-dep on the reads makes the
//     compiler emit fine-grained lgkmcnt(N) interleave (m97 behavior):
//     matrix pipe starts as soon as the first fragments land and overlaps
//     the remaining reads.  Safety (re-derived): every ds_read feeds an MFMA
//     in its own phase, so all reads of a half complete before that phase's
//     end barrier; ph2's stage of B0(kt+2) into the current buffer follows
//     the ph1-end barrier (all B reads done); ph3's A0(kt+2) follows the
//     ph2-end barrier (all A reads done); ph0/ph1 stage the opposite buffer.
//     Entry vmcnt(4) ledger identical to R9.
// ---------------------------------------------------------------------------
template <int EPI>
__global__ __launch_bounds__(512, 1) void gemm_8ph(
    const __hip_bfloat16* __restrict__ A,
    const __hip_bfloat16* __restrict__ Btb,
    const float* __restrict__ biasbase,
    void* __restrict__ outbase,
    const int* __restrict__ route,
    int Mdim, int Ndim, int Kdim, int tilesX) {
  const int bid  = blockIdx.x;
  const int b    = bid & 7;            // batch -> XCD
  const int tile = bid >> 3;
  const int bx   = tile % tilesX;
  const int by   = tile / tilesX;
  const int m = route[b];
  const __hip_bfloat16* Ab = A   + (size_t)b * Mdim * Kdim;
  const __hip_bfloat16* Bt = Btb + (size_t)m * Ndim * Kdim;
  const float* bias = biasbase + (size_t)m * Ndim;
  const int r0 = bx * 256;
  const int n0 = by * 256;

  __shared__ alignas(16) __hip_bfloat16 As[2][2][128 * 64];  // 64 KB
  __shared__ alignas(16) __hip_bfloat16 Bs[2][2][128 * 64];  // 64 KB

  const int t = threadIdx.x;
  const int w = t >> 6, l = t & 63;
  const int wm = w >> 2;               // 0..1  (M half, 128 rows)
  const int wn = w & 3;                // 0..3  (N quarter, 64 cols)

  const int srow = t >> 3;                     // 0..63
  const int scol = (t & 7) ^ ((t >> 3) & 7);   // inverse-swizzled 16B chunk

#define STAGE_AH(sb, ha, k0)                                                  \
  { async_copy16(Ab + (size_t)(r0 + (ha) * 128 + srow) * Kdim + (k0) + scol * 8, \
                 &As[sb][ha][(size_t)t * 8]);                                 \
    async_copy16(Ab + (size_t)(r0 + (ha) * 128 + 64 + srow) * Kdim + (k0) + scol * 8, \
                 &As[sb][ha][(size_t)(512 + t) * 8]); }
#define STAGE_BH(sb, hb, k0)                                                  \
  { async_copy16(Bt + (size_t)(n0 + (hb) * 128 + srow) * Kdim + (k0) + scol * 8, \
                 &Bs[sb][hb][(size_t)t * 8]);                                 \
    async_copy16(Bt + (size_t)(n0 + (hb) * 128 + 64 + srow) * Kdim + (k0) + scol * 8, \
                 &Bs[sb][hb][(size_t)(512 + t) * 8]); }

  const int lrow = l & 15, lq = l >> 4, lx = l & 7;

#define LOAD_A(mh)                                                            \
  { _Pragma("unroll")                                                         \
    for (int i = 0; i < 4; ++i) {                                             \
      const int row = ((mh) * 4 + i) * 16 + lrow;                             \
      aF[i][0] = *reinterpret_cast<const bf16x8*>(&aH[(row * 8 + ((0 + lq) ^ lx)) * 8]); \
      aF[i][1] = *reinterpret_cast<const bf16x8*>(&aH[(row * 8 + ((4 + lq) ^ lx)) * 8]); \
    } }
#define LOAD_B(nh)                                                            \
  { _Pragma("unroll")                                                         \
    for (int j = 0; j < 2; ++j) {                                             \
      const int row = (wn & 1) * 64 + ((nh) * 2 + j) * 16 + lrow;             \
      bF[nh][j][0] = *reinterpret_cast<const bf16x8*>(&bH[(row * 8 + ((0 + lq) ^ lx)) * 8]); \
      bF[nh][j][1] = *reinterpret_cast<const bf16x8*>(&bH[(row * 8 + ((4 + lq) ^ lx)) * 8]); \
    } }
#define MFMA_Q(mh, nh)                                                        \
  { __builtin_amdgcn_s_setprio(1);                                            \
    _Pragma("unroll")                                                         \
    for (int i = 0; i < 4; ++i)                                               \
      _Pragma("unroll")                                                       \
      for (int j = 0; j < 2; ++j) {                                           \
        acc[(mh) * 4 + i][(nh) * 2 + j] = __builtin_amdgcn_mfma_f32_16x16x32_bf16( \
            aF[i][0], bF[nh][j][0], acc[(mh) * 4 + i][(nh) * 2 + j], 0, 0, 0);\
        acc[(mh) * 4 + i][(nh) * 2 + j] = __builtin_amdgcn_mfma_f32_16x16x32_bf16( \
            aF[i][1], bF[nh][j][1], acc[(mh) * 4 + i][(nh) * 2 + j], 0, 0, 0);\
      }                                                                       \
    __builtin_amdgcn_s_setprio(0); }
#define BARSCHED  { __builtin_amdgcn_s_barrier(); __builtin_amdgcn_sched_barrier(0); }

  f32x4 acc[8][4] = {};
  const int nt = Kdim >> 6;

  STAGE_BH(0, 0, 0)
  STAGE_AH(0, 0, 0)
  STAGE_AH(0, 1, 0)
  STAGE_BH(0, 1, 0)
  if (nt > 1) { STAGE_BH(1, 0, 64) STAGE_AH(1, 0, 64) }

  for (int kt = 0; kt < nt; ++kt) {
    const int s = kt & 1;
    if (kt == nt - 1) { asm volatile("s_waitcnt vmcnt(0)" ::: "memory"); }
    else              { asm volatile("s_waitcnt vmcnt(4)" ::: "memory"); }
    BARSCHED

    const __hip_bfloat16* aH = As[s][wm];
    const __hip_bfloat16* bH = Bs[s][wn >> 1];
    bf16x8 aF[4][2], bF[2][2][2];

    // ph0: {read A0+B0; stage A1(kt+1)->opp; MFMA Q00} -> barrier
    LOAD_A(0)
    LOAD_B(0)
    if (kt + 1 < nt) STAGE_AH(s ^ 1, 1, (kt + 1) * 64)
    MFMA_Q(0, 0)
    BARSCHED

    // ph1: {read B1; stage B1(kt+1)->opp; MFMA Q01} -> barrier
    LOAD_B(1)
    if (kt + 1 < nt) STAGE_BH(s ^ 1, 1, (kt + 1) * 64)
    MFMA_Q(0, 1)
    BARSCHED

    // ph2: {read A1; stage B0(kt+2)->cur (B reads done at ph1 bar); Q10} -> barrier
    LOAD_A(1)
    if (kt + 2 < nt) STAGE_BH(s, 0, (kt + 2) * 64)
    MFMA_Q(1, 0)
    BARSCHED

    // ph3: {stage A0(kt+2)->cur (A reads done at ph2 bar); Q11}; loop-top bar
    if (kt + 2 < nt) STAGE_AH(s, 0, (kt + 2) * 64)
    MFMA_Q(1, 1)
  }
#undef STAGE_AH
#undef STAGE_BH
#undef LOAD_A
#undef LOAD_B
#undef MFMA_Q
#undef BARSCHED

  if (EPI == 0) {
    __hip_bfloat16* out = (__hip_bfloat16*)outbase + (size_t)b * Mdim * Ndim;
#pragma unroll
    for (int mb = 0; mb < 8; ++mb) {
      const int row = r0 + wm * 128 + mb * 16 + lq * 4;
#pragma unroll
      for (int nb = 0; nb < 4; ++nb) {
        const int col = n0 + wn * 64 + nb * 16 + lrow;
        const float bv = bias[col];
#pragma unroll
        for (int j = 0; j < 4; ++j) {
          float g = gelu_fast(acc[mb][nb][j] + bv);
          out[(size_t)(row + j) * Ndim + col] = __float2bfloat16(g);
        }
      }
    }
  } else {
    float* out = (float*)outbase + (size_t)b * Mdim * Ndim;
#pragma unroll
    for (int mb = 0; mb < 8; ++mb) {
      const int row = r0 + wm * 128 + mb * 16 + lq * 4;
#pragma unroll
      for (int nb = 0; nb < 4; ++nb) {
        const int col = n0 + wn * 64 + nb * 16 + lrow;
        const float bv = bias[col];
#pragma unroll
        for (int j = 0; j < 4; ++j)
          out[(size_t)(row + j) * Ndim + col] = acc[mb][nb][j] + bv;
      }
    }
  }
}

// ---------------------------------------------------------------------------
// 4b) GEMM2 — R6's proven gemm_db2 (BM=BN=128, BK=64), reverted (control).
// ---------------------------------------------------------------------------
template <int EPI>
__global__ __launch_bounds__(256, 2) void gemm_db2(
    const __hip_bfloat16* __restrict__ Abase,
    const __hip_bfloat16* __restrict__ Btbase,
    const float* __restrict__ biasbase,
    void* __restrict__ outbase,
    const int* __restrict__ route,
    int Mdim, int Ndim, int Kdim, int tilesX) {
  const int bid  = blockIdx.x;
  const int b    = bid & 7;
  const int tile = bid >> 3;
  const int bx   = tile % tilesX;
  const int by   = tile / tilesX;
  const int m = route[b];
  const __hip_bfloat16* A  = Abase  + (size_t)b * Mdim * Kdim;
  const __hip_bfloat16* Bt = Btbase + (size_t)m * Ndim * Kdim;
  const float* bias = biasbase + (size_t)m * Ndim;
  const int r0 = bx * 128;
  const int n0 = by * 128;

  __shared__ alignas(16) __hip_bfloat16 As[2][128 * 64];
  __shared__ alignas(16) __hip_bfloat16 Bs[2][128 * 64];

  const int t = threadIdx.x;
  const int w = t >> 6, l = t & 63;
  const int wr = w >> 1, wc = w & 1;

  const int srow = t >> 3;
  const int scol = (t & 7) ^ ((t >> 3) & 7);

#define STAGE(s_, k0)                                                         \
  { _Pragma("unroll")                                                         \
    for (int i = 0; i < 4; ++i)                                               \
      async_copy16(A + (size_t)(r0 + i * 32 + srow) * Kdim + (k0) + scol * 8, \
                   &As[s_][(i * 256 + t) * 8]);                               \
    _Pragma("unroll")                                                         \
    for (int i = 0; i < 4; ++i)                                               \
      async_copy16(Bt + (size_t)(n0 + i * 32 + srow) * Kdim + (k0) + scol * 8,\
                   &Bs[s_][(i * 256 + t) * 8]); }

  const int lrow = l & 15, lq = l >> 4, lx = l & 7;
  f32x4 acc[4][4] = {};
  const int nt = Kdim >> 6;

  STAGE(0, 0)

  for (int kt = 0; kt < nt; ++kt) {
    const int s = kt & 1;
    if (kt + 1 < nt) {
      STAGE(s ^ 1, (kt + 1) * 64)
      asm volatile("s_waitcnt vmcnt(8)" ::: "memory");
    } else {
      asm volatile("s_waitcnt vmcnt(0)" ::: "memory");
    }
    __builtin_amdgcn_s_barrier();
    __builtin_amdgcn_sched_barrier(0);

    const __hip_bfloat16* as_ = As[s];
    const __hip_bfloat16* bs_ = Bs[s];
    bf16x8 af[4][2], bfr[4][2];
#pragma unroll
    for (int mb = 0; mb < 4; ++mb) {
      const int row = wr * 64 + mb * 16 + lrow;
      af[mb][0] = *reinterpret_cast<const bf16x8*>(&as_[(row * 8 + ((0 + lq) ^ lx)) * 8]);
      af[mb][1] = *reinterpret_cast<const bf16x8*>(&as_[(row * 8 + ((4 + lq) ^ lx)) * 8]);
    }
#pragma unroll
    for (int nb = 0; nb < 4; ++nb) {
      const int row = wc * 64 + nb * 16 + lrow;
      bfr[nb][0] = *reinterpret_cast<const bf16x8*>(&bs_[(row * 8 + ((0 + lq) ^ lx)) * 8]);
      bfr[nb][1] = *reinterpret_cast<const bf16x8*>(&bs_[(row * 8 + ((4 + lq) ^ lx)) * 8]);
    }
#pragma unroll
    for (int mb = 0; mb < 4; ++mb)
#pragma unroll
      for (int nb = 0; nb < 4; ++nb) {
        acc[mb][nb] = __builtin_amdgcn_mfma_f32_16x16x32_bf16(
            af[mb][0], bfr[nb][0], acc[mb][nb], 0, 0, 0);
        acc[mb][nb] = __builtin_amdgcn_mfma_f32_16x16x32_bf16(
            af[mb][1], bfr[nb][1], acc[mb][nb], 0, 0, 0);
      }

    __builtin_amdgcn_sched_barrier(0);
    __builtin_amdgcn_s_barrier();
  }
#undef STAGE

  if (EPI == 0) {
    __hip_bfloat16* out = (__hip_bfloat16*)outbase + (size_t)b * Mdim * Ndim;
#pragma unroll
    for (int mb = 0; mb < 4; ++mb) {
      const int row = r0 + wr * 64 + mb * 16 + lq * 4;
#pragma unroll
      for (int nb = 0; nb < 4; ++nb) {
        const int col = n0 + wc * 64 + nb * 16 + lrow;
        const float bv = bias[col];
#pragma unroll
        for (int j = 0; j < 4; ++j) {
          float g = gelu_fast(acc[mb][nb][j] + bv);
          out[(size_t)(row + j) * Ndim + col] = __float2bfloat16(g);
        }
      }
    }
  } else {
    float* out = (float*)outbase + (size_t)b * Mdim * Ndim;
#pragma unroll
    for (int mb = 0; mb < 4; ++mb) {
      const int row = r0 + wr * 64 + mb * 16 + lq * 4;
#pragma unroll
      for (int nb = 0; nb < 4; ++nb) {
        const int col = n0 + wc * 64 + nb * 16 + lrow;
        const float bv = bias[col];
#pragma unroll
        for (int j = 0; j < 4; ++j)
          out[(size_t)(row + j) * Ndim + col] = acc[mb][nb][j] + bv;
      }
    }
  }
}

// ---------------------------------------------------------------------------
extern "C" void kernel_launch(void* const* d_in, const int* in_sizes, int n_in,
                              void* d_out, int out_size, void* d_ws, size_t ws_size,
                              hipStream_t stream) {
  const float* x      = (const float*)d_in[0];
  const float* cond   = (const float*)d_in[1];
  const int*   route  = (const int*)d_in[2];
  const float* W_cond = (const float*)d_in[3];
  const float* b_cond = (const float*)d_in[4];
  const float* W1     = (const float*)d_in[5];
  const float* b1     = (const float*)d_in[6];
  const float* W2     = (const float*)d_in[7];
  const float* b2     = (const float*)d_in[8];
  float* out = (float*)d_out;

  // workspace layout (bytes)
  const size_t SS_OFF   = 0;
  const size_t XMOD_OFF = 32768;
  const size_t W1T_OFF  = XMOD_OFF + (size_t)BATCH * NTOK * DDIM * 2;
  const size_t W2T_OFF  = W1T_OFF + (size_t)NEXP * DDIM * DFFDIM * 2;
  const size_t H_OFF    = W2T_OFF + (size_t)NEXP * DFFDIM * DDIM * 2;
  const size_t NEED     = H_OFF + (size_t)BATCH * NTOK * DFFDIM * 2;
  if (ws_size < NEED) return;

  char* ws = (char*)d_ws;
  float* ss            = (float*)(ws + SS_OFF);
  __hip_bfloat16* xmod = (__hip_bfloat16*)(ws + XMOD_OFF);
  __hip_bfloat16* w1t  = (__hip_bfloat16*)(ws + W1T_OFF);
  __hip_bfloat16* w2t  = (__hip_bfloat16*)(ws + W2T_OFF);
  __hip_bfloat16* h    = (__hip_bfloat16*)(ws + H_OFF);

  // 1) cond modulation
  mod_kernel<<<dim3(2 * DDIM / 64, BATCH), 256, 0, stream>>>(cond, route, W_cond, b_cond, ss);

  // 2) FiLM -> bf16
  {
    const size_t groups = (size_t)BATCH * NTOK * DDIM / 4;
    film_kernel<<<(unsigned)(groups / 256), 256, 0, stream>>>(x, ss, xmod);
  }

  // 3) weight transpose+convert (routed experts only)
  transpose_cvt<<<dim3(DFFDIM / 32, DDIM / 32, NEXP), dim3(32, 8), 0, stream>>>(W1, w1t, DDIM, DFFDIM, route);
  transpose_cvt<<<dim3(DDIM / 32, DFFDIM / 32, NEXP), dim3(32, 8), 0, stream>>>(W2, w2t, DFFDIM, DDIM, route);

  // 4) GEMM1 (4-barrier 8-phase): grid 8*8*8 = 512 blocks
  gemm_8ph<0><<<(NTOK / 256) * (DFFDIM / 256) * BATCH, 512, 0, stream>>>(
      xmod, w1t, b1, h, route, NTOK, DFFDIM, DDIM, NTOK / 256);

  // 5) GEMM2 (R6 control, reverted): grid 16*4*8 = 512 blocks
  gemm_db2<1><<<(NTOK / 128) * (DDIM / 128) * BATCH, 256, 0, stream>>>(
      h, w2t, b2, out, route, NTOK, DDIM, DFFDIM, NTOK / 128);
}